// Round 9
// baseline (392.102 us; speedup 1.0000x reference)
//
#include <hip/hip_runtime.h>

typedef unsigned short u16;
typedef __attribute__((ext_vector_type(8))) short short8;
typedef __attribute__((ext_vector_type(4))) float floatx4;

#define B_ 128
#define S_ 500
#define FCIN 16000
#define HID 1024
#define QSCL 0.72134752044448169f   // 0.5 * log2(e)

__device__ __forceinline__ float bf2f(u16 u) {
    union { unsigned u32; float f; } x;
    x.u32 = ((unsigned)u) << 16;
    return x.f;
}
__device__ __forceinline__ u16 f2bf(float f) {
    union { float f; unsigned u; } x;
    x.f = f;
    unsigned u = x.u;
    return (u16)((u + 0x7fff + ((u >> 16) & 1)) >> 16);
}

// ---------------------------------------------------------------------------
// K1: fused QKV + MFMA attention. Block = (b,h), 256 thr / 4 waves.
// v10 = v9 (proven PASS, attn 190us) + ones-row denominator ONLY.
//   Evidence matrix r5-r8: all three FAILs shared EXP2+unroll1 (v6/v7/v8);
//   v9 (neither) passes. EXP2 dropped permanently (exp2f already lowers to
//   bare v_exp_f32; implicated in rolled-loop miscompile). Ones-row was
//   confounded in v6 -> clean single-delta trial here:
//   sVT row 4 = 1.0 for keys<500 (0 for pad keys, which have P=exp(0)=1 and
//   must be excluded). PV MFMA then emits denominator in C row 4 = lanes
//   16-31 acc[0]. Deletes 8 rs-adds + select per c-iter + 2 shfl_xor.
// ---------------------------------------------------------------------------
__global__ __launch_bounds__(256) void attn_fused_mfma(
    const float* __restrict__ x,
    const float* __restrict__ Wq, const float* __restrict__ bq,
    const float* __restrict__ Wk, const float* __restrict__ bk,
    const float* __restrict__ Wv, const float* __restrict__ bv,
    u16* __restrict__ avbf)
{
    __shared__ float sWb[12 * 32];   // rows 0-3 Wq, 4-7 Wk, 8-11 Wv (head h)
    __shared__ float sBb[12];
    __shared__ u16 sQ8[512 * 8];     // [q][qh0..3, ql0..3]
    __shared__ u16 sK8[512 * 8];     // [key][kh0..3, kl0..3]
    __shared__ u16 sVT[5 * 520];     // [vcol][key]; row 4 = ones (keys<500)

    int tid = threadIdx.x;
    int bh = blockIdx.x, b = bh >> 3, h = bh & 7;

    for (int i = tid; i < 384; i += 256) {
        int r = i >> 5, d = i & 31;
        const float* src = (r < 4) ? (Wq + (h * 4 + r) * 32)
                         : (r < 8) ? (Wk + (h * 4 + r - 4) * 32)
                                   : (Wv + (h * 4 + r - 8) * 32);
        sWb[r * 32 + d] = src[d];
    }
    if (tid < 12)
        sBb[tid] = (tid < 4) ? bq[h * 4 + tid]
                 : (tid < 8) ? bk[h * 4 + tid - 4] : bv[h * 4 + tid - 8];
    if (tid < 32) sVT[(tid >> 3) * 520 + 512 + (tid & 7)] = 0;
    for (int i = tid; i < 520; i += 256)             // ones row (denominator);
        sVT[4 * 520 + i] = (i < S_) ? (u16)0x3F80 : (u16)0;  // pad keys excluded
    __syncthreads();

    for (int s = tid; s < 512; s += 256) {
        bool valid = (s < S_);
        const float* xr = x + ((size_t)b * S_ + (valid ? s : 0)) * 32;
        float4 xv[8];
#pragma unroll
        for (int cc = 0; cc < 8; ++cc) xv[cc] = *(const float4*)(xr + cc * 4);
        short8 qv, kv;
#pragma unroll
        for (int r = 0; r < 12; ++r) {
            float acc = sBb[r];
            const float4* w4 = (const float4*)(sWb + r * 32);
#pragma unroll
            for (int cc = 0; cc < 8; ++cc) {
                float4 w = w4[cc];
                acc += xv[cc].x * w.x + xv[cc].y * w.y
                     + xv[cc].z * w.z + xv[cc].w * w.w;
            }
            if (!valid) acc = 0.f;
            if (r < 4) {
                float v = acc * QSCL;
                u16 hi = f2bf(v);
                qv[r]     = (short)hi;
                qv[4 + r] = (short)f2bf(v - bf2f(hi));
            } else if (r < 8) {
                int j = r - 4;
                u16 hi = f2bf(acc);
                kv[j]     = (short)hi;
                kv[4 + j] = (short)f2bf(acc - bf2f(hi));
            } else {
                sVT[(r - 8) * 520 + s] = f2bf(acc);
            }
        }
        *(short8*)(sQ8 + s * 8) = qv;    // one b128 store, conflict-free
        *(short8*)(sK8 + s * 8) = kv;
    }
    __syncthreads();

    int wid = tid >> 6, lane = tid & 63;
    int ln = lane & 15, kq = lane >> 4;
    const short8 z8 = {0, 0, 0, 0, 0, 0, 0, 0};
    floatx4 zero = {0.f, 0.f, 0.f, 0.f};

    for (int i = 0; i < 8; ++i) {
        int qt = wid + 4 * i;                        // q-tile [0,32)
        short8 qf = z8;
        if (kq == 0) qf = *(const short8*)(sQ8 + (qt * 16 + ln) * 8);
        // swapped halves: cross terms kh*ql + kl*qh via B-side swap
        short8 qfs = __builtin_shufflevector(qf, qf, 4, 5, 6, 7, 0, 1, 2, 3);

        floatx4 acc = zero;

        for (int c = 0; c < 16; ++c) {
            short8 ka = z8, kb = z8;
            if (kq == 0) {
                ka = *(const short8*)(sK8 + ((2 * c) * 16 + ln) * 8);
                kb = *(const short8*)(sK8 + ((2 * c + 1) * 16 + ln) * 8);
            }

            floatx4 s1 = __builtin_amdgcn_mfma_f32_16x16x32_bf16(ka, qf, zero, 0, 0, 0);
            s1 = __builtin_amdgcn_mfma_f32_16x16x32_bf16(ka, qfs, s1, 0, 0, 0);
            floatx4 s2 = __builtin_amdgcn_mfma_f32_16x16x32_bf16(kb, qf, zero, 0, 0, 0);
            s2 = __builtin_amdgcn_mfma_f32_16x16x32_bf16(kb, qfs, s2, 0, 0, 0);

            // C layout: col=ln=q, row=kq*4+r = local key
            float e10 = exp2f(s1[0]), e11 = exp2f(s1[1]),
                  e12 = exp2f(s1[2]), e13 = exp2f(s1[3]);
            float e20 = exp2f(s2[0]), e21 = exp2f(s2[1]),
                  e22 = exp2f(s2[2]), e23 = exp2f(s2[3]);

            // pack P to bf16 pairs: d1a={k 4kq,4kq+1} d1b={k 4kq+2,4kq+3}
            //                       d2a/d2b same for keys 16+4kq..
            unsigned d1a, d1b, d2a, d2b;
            asm("v_cvt_pk_bf16_f32 %0, %1, %2" : "=v"(d1a) : "v"(e10), "v"(e11));
            asm("v_cvt_pk_bf16_f32 %0, %1, %2" : "=v"(d1b) : "v"(e12), "v"(e13));
            asm("v_cvt_pk_bf16_f32 %0, %1, %2" : "=v"(d2a) : "v"(e20), "v"(e21));
            asm("v_cvt_pk_bf16_f32 %0, %1, %2" : "=v"(d2b) : "v"(e22), "v"(e23));

            // redistribute so lane(ln,kq) holds P^T[k=kq*8..kq*8+7][q=ln]:
            // swap upper 32 lanes of d1* with lower 32 of d2*  (kq2<-d2(kq0) etc)
            asm("v_permlane32_swap_b32 %0, %1" : "+v"(d1a), "+v"(d2a));
            asm("v_permlane32_swap_b32 %0, %1" : "+v"(d1b), "+v"(d2b));
            // swap odd 16-rows of d1* with even 16-rows of d2*
            asm("v_permlane16_swap_b32 %0, %1" : "+v"(d1a), "+v"(d2a));
            asm("v_permlane16_swap_b32 %0, %1" : "+v"(d1b), "+v"(d2b));

            union { short8 s8; unsigned u[4]; } pu;
            pu.u[0] = d1a; pu.u[1] = d1b; pu.u[2] = d2a; pu.u[3] = d2b;
            short8 pf = pu.s8;

            // A rows 0-3 = V cols, row 4 = ones (0 for pad keys) ->
            // C row 4 accumulates the softmax denominator.
            short8 vf = z8;
            if (ln < 5)
                vf = *(const short8*)(sVT + ln * 520 + c * 32 + kq * 8);
            acc = __builtin_amdgcn_mfma_f32_16x16x32_bf16(vf, pf, acc, 0, 0, 0);
        }

        // denominator = C row 4 col ln = lane (16+ln) acc[0]
        float rs = __shfl(acc[0], ln + 16, 64);

        int q = qt * 16 + ln;
        if (kq == 0 && q < S_) {                     // D rows 0-3 = vcols
            float inv = 1.0f / rs;
            uint2 pk;
            pk.x = (unsigned)f2bf(acc[0] * inv) | ((unsigned)f2bf(acc[1] * inv) << 16);
            pk.y = (unsigned)f2bf(acc[2] * inv) | ((unsigned)f2bf(acc[3] * inv) << 16);
            *(uint2*)(avbf + ((size_t)(b * S_ + q) * 32 + h * 4)) = pk;
        }
    }
}

// ---------------------------------------------------------------------------
// K2: output projection via MFMA: flat = av @ Wo^T + bo (bf16 out).
// Also inits hidden[m][j] = b1[j] for fc1's atomic accumulation.
// ---------------------------------------------------------------------------
__global__ __launch_bounds__(256) void proj_mfma(
    const u16* __restrict__ avbf, const float* __restrict__ Wo,
    const float* __restrict__ bo, const float* __restrict__ b1,
    u16* __restrict__ flat, float* __restrict__ hidden)
{
    int tid = threadIdx.x;
    int gid = blockIdx.x * 256 + tid;
    if (gid < B_ * HID) hidden[gid] = b1[gid & (HID - 1)];

    int wid = tid >> 6, lane = tid & 63;
    int lm = lane & 15, kq = lane >> 4;
    int m0 = (blockIdx.x * 4 + wid) * 16;

    short8 af = *(const short8*)(avbf + (size_t)(m0 + lm) * 32 + kq * 8);
    floatx4 zero = {0.f, 0.f, 0.f, 0.f};
#pragma unroll
    for (int t2 = 0; t2 < 2; ++t2) {
        int d = t2 * 16 + lm;
        const float* wr = Wo + d * 32 + kq * 8;
        float4 w0 = *(const float4*)(wr);
        float4 w1 = *(const float4*)(wr + 4);
        short8 bf;
        bf[0] = (short)f2bf(w0.x); bf[1] = (short)f2bf(w0.y);
        bf[2] = (short)f2bf(w0.z); bf[3] = (short)f2bf(w0.w);
        bf[4] = (short)f2bf(w1.x); bf[5] = (short)f2bf(w1.y);
        bf[6] = (short)f2bf(w1.z); bf[7] = (short)f2bf(w1.w);
        floatx4 acc = __builtin_amdgcn_mfma_f32_16x16x32_bf16(af, bf, zero, 0, 0, 0);
        float bias = bo[d];
#pragma unroll
        for (int r = 0; r < 4; ++r) {
            int row = m0 + kq * 4 + r;
            flat[(size_t)row * 32 + d] = f2bf(acc[r] + bias);
        }
    }
}

// ---------------------------------------------------------------------------
// K3: FC1 via MFMA split-K (25 k-chunks x 16 n-groups = 400 blocks).
// ---------------------------------------------------------------------------
__global__ __launch_bounds__(256) void fc1_mfma(
    const u16* __restrict__ flatbf, const float* __restrict__ W1,
    float* __restrict__ hidden)
{
    int tid = threadIdx.x;
    int wid = tid >> 6, lane = tid & 63;
    int lm = lane & 15, kq = lane >> 4;
    int ng = blockIdx.x & 15, kc = blockIdx.x >> 4;   // kc in [0,25)
    int n0 = ng * 64 + wid * 16;

    floatx4 acc[8];
#pragma unroll
    for (int mt = 0; mt < 8; ++mt) acc[mt] = (floatx4){0.f, 0.f, 0.f, 0.f};

    const float* wrow = W1 + (size_t)(n0 + lm) * FCIN;
    const u16*  abase = flatbf + lm * FCIN;

    for (int step = 0; step < 20; ++step) {
        int kk = kc * 640 + step * 32 + kq * 8;
        float4 w0 = *(const float4*)(wrow + kk);
        float4 w1 = *(const float4*)(wrow + kk + 4);
        short8 bfr;
        bfr[0] = (short)f2bf(w0.x); bfr[1] = (short)f2bf(w0.y);
        bfr[2] = (short)f2bf(w0.z); bfr[3] = (short)f2bf(w0.w);
        bfr[4] = (short)f2bf(w1.x); bfr[5] = (short)f2bf(w1.y);
        bfr[6] = (short)f2bf(w1.z); bfr[7] = (short)f2bf(w1.w);
#pragma unroll
        for (int mt = 0; mt < 8; ++mt) {
            short8 afr = *(const short8*)(abase + mt * 16 * FCIN + kk);
            acc[mt] = __builtin_amdgcn_mfma_f32_16x16x32_bf16(afr, bfr, acc[mt], 0, 0, 0);
        }
    }

    int j = n0 + lm;
#pragma unroll
    for (int mt = 0; mt < 8; ++mt) {
#pragma unroll
        for (int r = 0; r < 4; ++r) {
            int m = mt * 16 + kq * 4 + r;
            atomicAdd(&hidden[m * HID + j], acc[mt][r]);
        }
    }
}

// ---------------------------------------------------------------------------
// K4: FC2 + FC3 (fp32 VALU). d_out fp32: [0,8192)=out1, [8192,8448)=out.
// ---------------------------------------------------------------------------
__global__ __launch_bounds__(256) void fc2_kernel(
    const float* __restrict__ hidden,
    const float* __restrict__ W2, const float* __restrict__ b2,
    const float* __restrict__ W3, const float* __restrict__ b3,
    float* __restrict__ out)
{
    int tid = threadIdx.x;
    int c = tid & 63;
    int m = blockIdx.x * 4 + (tid >> 6);
    const float* hrow = hidden + m * HID;
    const float* wrow = W2 + c * HID;

    float acc = b2[c];
    for (int p = 0; p < HID; p += 4) {
        float4 wv = *(const float4*)(wrow + p);
        float4 hv = *(const float4*)(hrow + p);
        acc += hv.x * wv.x + hv.y * wv.y + hv.z * wv.z + hv.w * wv.w;
    }
    out[m * 64 + c] = acc;

    float t0 = acc * W3[c];
    float t1 = acc * W3[64 + c];
#pragma unroll
    for (int off = 32; off > 0; off >>= 1) {
        t0 += __shfl_down(t0, off, 64);
        t1 += __shfl_down(t1, off, 64);
    }
    if (c == 0) {
        float2 pk;
        pk.x = t0 + b3[0];
        pk.y = t1 + b3[1];
        *(float2*)(out + 8192 + m * 2) = pk;
    }
}

// ---------------------------------------------------------------------------
extern "C" void kernel_launch(void* const* d_in, const int* in_sizes, int n_in,
                              void* d_out, int out_size, void* d_ws, size_t ws_size,
                              hipStream_t stream) {
    const float* x  = (const float*)d_in[0];
    const float* Wq = (const float*)d_in[1];
    const float* bq = (const float*)d_in[2];
    const float* Wk = (const float*)d_in[3];
    const float* bk = (const float*)d_in[4];
    const float* Wv = (const float*)d_in[5];
    const float* bv = (const float*)d_in[6];
    const float* Wo = (const float*)d_in[7];
    const float* bo = (const float*)d_in[8];
    const float* W1 = (const float*)d_in[9];
    const float* b1 = (const float*)d_in[10];
    const float* W2 = (const float*)d_in[11];
    const float* b2 = (const float*)d_in[12];
    const float* W3 = (const float*)d_in[13];
    const float* b3 = (const float*)d_in[14];
    float* out = (float*)d_out;

    // ws layout (bytes), total 8,716,288:
    //   [0,         4,096,000)  avbf bf16 [64000][32]
    //   [4,096,000, 8,192,000)  flat bf16 [128][16000]
    //   [8,192,000, 8,716,288)  hidden fp32 [128][1024]
    u16*   avbf   = (u16*)d_ws;
    u16*   flat   = (u16*)((char*)d_ws + 4096000);
    float* hidden = (float*)((char*)d_ws + 8192000);

    attn_fused_mfma<<<dim3(1024), dim3(256), 0, stream>>>(
        x, Wq, bq, Wk, bk, Wv, bv, avbf);
    proj_mfma <<<dim3(1000), dim3(256), 0, stream>>>(avbf, Wo, bo, b1, flat, hidden);
    fc1_mfma  <<<dim3(400),  dim3(256), 0, stream>>>(flat, W1, hidden);
    fc2_kernel<<<dim3(32),   dim3(256), 0, stream>>>(hidden, W2, b2, W3, b3, out);
}

// Round 10
// 373.267 us; speedup vs baseline: 1.0505x; 1.0505x over previous
//
#include <hip/hip_runtime.h>

typedef unsigned short u16;
typedef __attribute__((ext_vector_type(8))) short short8;
typedef __attribute__((ext_vector_type(4))) float floatx4;

#define B_ 128
#define S_ 500
#define FCIN 16000
#define HID 1024
#define QSCL 0.72134752044448169f   // 0.5 * log2(e)

__device__ __forceinline__ float bf2f(u16 u) {
    union { unsigned u32; float f; } x;
    x.u32 = ((unsigned)u) << 16;
    return x.f;
}
__device__ __forceinline__ u16 f2bf(float f) {
    union { float f; unsigned u; } x;
    x.f = f;
    unsigned u = x.u;
    return (u16)((u + 0x7fff + ((u >> 16) & 1)) >> 16);
}

// ---------------------------------------------------------------------------
// K1: fused QKV + MFMA attention. Block = (b,h), 256 thr / 4 waves.
// v11 = v10 (PASS: permlane P-exchange, ones-row denominator) + 2-way q-tile
//   interleave. Rationale: 1 wave/SIMD (220+accum VGPR) with MfmaUtil 8% +
//   VALUBusy 44% -> ~50% dependency stalls and no TLP to hide them; bounds
//   are a closed path (RF-split spill, r1/r2/r4). Two q-tiles per c-body
//   give two independent score->exp->pack->PV chains that hide each other's
//   latency, AND share the ka/kb/vf LDS loads (halves c-loop LDS traffic).
//   +~32 arch VGPR at 1 wave/SIMD (512 ceiling) -> no occupancy change.
// ---------------------------------------------------------------------------
__global__ __launch_bounds__(256) void attn_fused_mfma(
    const float* __restrict__ x,
    const float* __restrict__ Wq, const float* __restrict__ bq,
    const float* __restrict__ Wk, const float* __restrict__ bk,
    const float* __restrict__ Wv, const float* __restrict__ bv,
    u16* __restrict__ avbf)
{
    __shared__ float sWb[12 * 32];   // rows 0-3 Wq, 4-7 Wk, 8-11 Wv (head h)
    __shared__ float sBb[12];
    __shared__ u16 sQ8[512 * 8];     // [q][qh0..3, ql0..3]
    __shared__ u16 sK8[512 * 8];     // [key][kh0..3, kl0..3]
    __shared__ u16 sVT[5 * 520];     // [vcol][key]; row 4 = ones (keys<500)

    int tid = threadIdx.x;
    int bh = blockIdx.x, b = bh >> 3, h = bh & 7;

    for (int i = tid; i < 384; i += 256) {
        int r = i >> 5, d = i & 31;
        const float* src = (r < 4) ? (Wq + (h * 4 + r) * 32)
                         : (r < 8) ? (Wk + (h * 4 + r - 4) * 32)
                                   : (Wv + (h * 4 + r - 8) * 32);
        sWb[r * 32 + d] = src[d];
    }
    if (tid < 12)
        sBb[tid] = (tid < 4) ? bq[h * 4 + tid]
                 : (tid < 8) ? bk[h * 4 + tid - 4] : bv[h * 4 + tid - 8];
    if (tid < 32) sVT[(tid >> 3) * 520 + 512 + (tid & 7)] = 0;
    for (int i = tid; i < 520; i += 256)             // ones row (denominator);
        sVT[4 * 520 + i] = (i < S_) ? (u16)0x3F80 : (u16)0;  // pad keys excluded
    __syncthreads();

    for (int s = tid; s < 512; s += 256) {
        bool valid = (s < S_);
        const float* xr = x + ((size_t)b * S_ + (valid ? s : 0)) * 32;
        float4 xv[8];
#pragma unroll
        for (int cc = 0; cc < 8; ++cc) xv[cc] = *(const float4*)(xr + cc * 4);
        short8 qv, kv;
#pragma unroll
        for (int r = 0; r < 12; ++r) {
            float acc = sBb[r];
            const float4* w4 = (const float4*)(sWb + r * 32);
#pragma unroll
            for (int cc = 0; cc < 8; ++cc) {
                float4 w = w4[cc];
                acc += xv[cc].x * w.x + xv[cc].y * w.y
                     + xv[cc].z * w.z + xv[cc].w * w.w;
            }
            if (!valid) acc = 0.f;
            if (r < 4) {
                float v = acc * QSCL;
                u16 hi = f2bf(v);
                qv[r]     = (short)hi;
                qv[4 + r] = (short)f2bf(v - bf2f(hi));
            } else if (r < 8) {
                int j = r - 4;
                u16 hi = f2bf(acc);
                kv[j]     = (short)hi;
                kv[4 + j] = (short)f2bf(acc - bf2f(hi));
            } else {
                sVT[(r - 8) * 520 + s] = f2bf(acc);
            }
        }
        *(short8*)(sQ8 + s * 8) = qv;    // one b128 store, conflict-free
        *(short8*)(sK8 + s * 8) = kv;
    }
    __syncthreads();

    int wid = tid >> 6, lane = tid & 63;
    int ln = lane & 15, kq = lane >> 4;
    const short8 z8 = {0, 0, 0, 0, 0, 0, 0, 0};
    floatx4 zero = {0.f, 0.f, 0.f, 0.f};

    for (int ii = 0; ii < 4; ++ii) {
        int qtA = wid + 8 * ii;                      // q-tiles [0,32), pairwise
        int qtB = qtA + 4;
        short8 qfA = z8, qfB = z8;
        if (kq == 0) {
            qfA = *(const short8*)(sQ8 + (qtA * 16 + ln) * 8);
            qfB = *(const short8*)(sQ8 + (qtB * 16 + ln) * 8);
        }
        // swapped halves: cross terms kh*ql + kl*qh via B-side swap
        short8 qfsA = __builtin_shufflevector(qfA, qfA, 4, 5, 6, 7, 0, 1, 2, 3);
        short8 qfsB = __builtin_shufflevector(qfB, qfB, 4, 5, 6, 7, 0, 1, 2, 3);

        floatx4 accA = zero, accB = zero;

        for (int c = 0; c < 16; ++c) {
            short8 ka = z8, kb = z8;
            if (kq == 0) {
                ka = *(const short8*)(sK8 + ((2 * c) * 16 + ln) * 8);
                kb = *(const short8*)(sK8 + ((2 * c + 1) * 16 + ln) * 8);
            }

            // two independent score chains sharing ka/kb
            floatx4 s1A = __builtin_amdgcn_mfma_f32_16x16x32_bf16(ka, qfA, zero, 0, 0, 0);
            s1A = __builtin_amdgcn_mfma_f32_16x16x32_bf16(ka, qfsA, s1A, 0, 0, 0);
            floatx4 s2A = __builtin_amdgcn_mfma_f32_16x16x32_bf16(kb, qfA, zero, 0, 0, 0);
            s2A = __builtin_amdgcn_mfma_f32_16x16x32_bf16(kb, qfsA, s2A, 0, 0, 0);
            floatx4 s1B = __builtin_amdgcn_mfma_f32_16x16x32_bf16(ka, qfB, zero, 0, 0, 0);
            s1B = __builtin_amdgcn_mfma_f32_16x16x32_bf16(ka, qfsB, s1B, 0, 0, 0);
            floatx4 s2B = __builtin_amdgcn_mfma_f32_16x16x32_bf16(kb, qfB, zero, 0, 0, 0);
            s2B = __builtin_amdgcn_mfma_f32_16x16x32_bf16(kb, qfsB, s2B, 0, 0, 0);

            // C layout: col=ln=q, row=kq*4+r = local key
            float eA10 = exp2f(s1A[0]), eA11 = exp2f(s1A[1]),
                  eA12 = exp2f(s1A[2]), eA13 = exp2f(s1A[3]);
            float eA20 = exp2f(s2A[0]), eA21 = exp2f(s2A[1]),
                  eA22 = exp2f(s2A[2]), eA23 = exp2f(s2A[3]);
            float eB10 = exp2f(s1B[0]), eB11 = exp2f(s1B[1]),
                  eB12 = exp2f(s1B[2]), eB13 = exp2f(s1B[3]);
            float eB20 = exp2f(s2B[0]), eB21 = exp2f(s2B[1]),
                  eB22 = exp2f(s2B[2]), eB23 = exp2f(s2B[3]);

            unsigned dA1a, dA1b, dA2a, dA2b, dB1a, dB1b, dB2a, dB2b;
            asm("v_cvt_pk_bf16_f32 %0, %1, %2" : "=v"(dA1a) : "v"(eA10), "v"(eA11));
            asm("v_cvt_pk_bf16_f32 %0, %1, %2" : "=v"(dA1b) : "v"(eA12), "v"(eA13));
            asm("v_cvt_pk_bf16_f32 %0, %1, %2" : "=v"(dA2a) : "v"(eA20), "v"(eA21));
            asm("v_cvt_pk_bf16_f32 %0, %1, %2" : "=v"(dA2b) : "v"(eA22), "v"(eA23));
            asm("v_cvt_pk_bf16_f32 %0, %1, %2" : "=v"(dB1a) : "v"(eB10), "v"(eB11));
            asm("v_cvt_pk_bf16_f32 %0, %1, %2" : "=v"(dB1b) : "v"(eB12), "v"(eB13));
            asm("v_cvt_pk_bf16_f32 %0, %1, %2" : "=v"(dB2a) : "v"(eB20), "v"(eB21));
            asm("v_cvt_pk_bf16_f32 %0, %1, %2" : "=v"(dB2b) : "v"(eB22), "v"(eB23));

            // redistribute so lane(ln,kq) holds P^T[k=kq*8..kq*8+7][q=ln]
            asm("v_permlane32_swap_b32 %0, %1" : "+v"(dA1a), "+v"(dA2a));
            asm("v_permlane32_swap_b32 %0, %1" : "+v"(dA1b), "+v"(dA2b));
            asm("v_permlane16_swap_b32 %0, %1" : "+v"(dA1a), "+v"(dA2a));
            asm("v_permlane16_swap_b32 %0, %1" : "+v"(dA1b), "+v"(dA2b));
            asm("v_permlane32_swap_b32 %0, %1" : "+v"(dB1a), "+v"(dB2a));
            asm("v_permlane32_swap_b32 %0, %1" : "+v"(dB1b), "+v"(dB2b));
            asm("v_permlane16_swap_b32 %0, %1" : "+v"(dB1a), "+v"(dB2a));
            asm("v_permlane16_swap_b32 %0, %1" : "+v"(dB1b), "+v"(dB2b));

            union { short8 s8; unsigned u[4]; } puA, puB;
            puA.u[0] = dA1a; puA.u[1] = dA1b; puA.u[2] = dA2a; puA.u[3] = dA2b;
            puB.u[0] = dB1a; puB.u[1] = dB1b; puB.u[2] = dB2a; puB.u[3] = dB2b;
            short8 pfA = puA.s8, pfB = puB.s8;

            // A rows 0-3 = V cols, row 4 = ones (0 for pad keys) ->
            // C row 4 accumulates the softmax denominator. vf shared A/B.
            short8 vf = z8;
            if (ln < 5)
                vf = *(const short8*)(sVT + ln * 520 + c * 32 + kq * 8);
            accA = __builtin_amdgcn_mfma_f32_16x16x32_bf16(vf, pfA, accA, 0, 0, 0);
            accB = __builtin_amdgcn_mfma_f32_16x16x32_bf16(vf, pfB, accB, 0, 0, 0);
        }

        // denominator = C row 4 col ln = lane (16+ln) acc[0]
        float rsA = __shfl(accA[0], ln + 16, 64);
        float rsB = __shfl(accB[0], ln + 16, 64);

        int qA = qtA * 16 + ln;
        if (kq == 0 && qA < S_) {                    // D rows 0-3 = vcols
            float inv = 1.0f / rsA;
            uint2 pk;
            pk.x = (unsigned)f2bf(accA[0] * inv) | ((unsigned)f2bf(accA[1] * inv) << 16);
            pk.y = (unsigned)f2bf(accA[2] * inv) | ((unsigned)f2bf(accA[3] * inv) << 16);
            *(uint2*)(avbf + ((size_t)(b * S_ + qA) * 32 + h * 4)) = pk;
        }
        int qB = qtB * 16 + ln;
        if (kq == 0 && qB < S_) {
            float inv = 1.0f / rsB;
            uint2 pk;
            pk.x = (unsigned)f2bf(accB[0] * inv) | ((unsigned)f2bf(accB[1] * inv) << 16);
            pk.y = (unsigned)f2bf(accB[2] * inv) | ((unsigned)f2bf(accB[3] * inv) << 16);
            *(uint2*)(avbf + ((size_t)(b * S_ + qB) * 32 + h * 4)) = pk;
        }
    }
}

// ---------------------------------------------------------------------------
// K2: output projection via MFMA: flat = av @ Wo^T + bo (bf16 out).
// Also inits hidden[m][j] = b1[j] for fc1's atomic accumulation.
// ---------------------------------------------------------------------------
__global__ __launch_bounds__(256) void proj_mfma(
    const u16* __restrict__ avbf, const float* __restrict__ Wo,
    const float* __restrict__ bo, const float* __restrict__ b1,
    u16* __restrict__ flat, float* __restrict__ hidden)
{
    int tid = threadIdx.x;
    int gid = blockIdx.x * 256 + tid;
    if (gid < B_ * HID) hidden[gid] = b1[gid & (HID - 1)];

    int wid = tid >> 6, lane = tid & 63;
    int lm = lane & 15, kq = lane >> 4;
    int m0 = (blockIdx.x * 4 + wid) * 16;

    short8 af = *(const short8*)(avbf + (size_t)(m0 + lm) * 32 + kq * 8);
    floatx4 zero = {0.f, 0.f, 0.f, 0.f};
#pragma unroll
    for (int t2 = 0; t2 < 2; ++t2) {
        int d = t2 * 16 + lm;
        const float* wr = Wo + d * 32 + kq * 8;
        float4 w0 = *(const float4*)(wr);
        float4 w1 = *(const float4*)(wr + 4);
        short8 bf;
        bf[0] = (short)f2bf(w0.x); bf[1] = (short)f2bf(w0.y);
        bf[2] = (short)f2bf(w0.z); bf[3] = (short)f2bf(w0.w);
        bf[4] = (short)f2bf(w1.x); bf[5] = (short)f2bf(w1.y);
        bf[6] = (short)f2bf(w1.z); bf[7] = (short)f2bf(w1.w);
        floatx4 acc = __builtin_amdgcn_mfma_f32_16x16x32_bf16(af, bf, zero, 0, 0, 0);
        float bias = bo[d];
#pragma unroll
        for (int r = 0; r < 4; ++r) {
            int row = m0 + kq * 4 + r;
            flat[(size_t)row * 32 + d] = f2bf(acc[r] + bias);
        }
    }
}

// ---------------------------------------------------------------------------
// K3: FC1 via MFMA split-K (25 k-chunks x 16 n-groups = 400 blocks).
// ---------------------------------------------------------------------------
__global__ __launch_bounds__(256) void fc1_mfma(
    const u16* __restrict__ flatbf, const float* __restrict__ W1,
    float* __restrict__ hidden)
{
    int tid = threadIdx.x;
    int wid = tid >> 6, lane = tid & 63;
    int lm = lane & 15, kq = lane >> 4;
    int ng = blockIdx.x & 15, kc = blockIdx.x >> 4;   // kc in [0,25)
    int n0 = ng * 64 + wid * 16;

    floatx4 acc[8];
#pragma unroll
    for (int mt = 0; mt < 8; ++mt) acc[mt] = (floatx4){0.f, 0.f, 0.f, 0.f};

    const float* wrow = W1 + (size_t)(n0 + lm) * FCIN;
    const u16*  abase = flatbf + lm * FCIN;

    for (int step = 0; step < 20; ++step) {
        int kk = kc * 640 + step * 32 + kq * 8;
        float4 w0 = *(const float4*)(wrow + kk);
        float4 w1 = *(const float4*)(wrow + kk + 4);
        short8 bfr;
        bfr[0] = (short)f2bf(w0.x); bfr[1] = (short)f2bf(w0.y);
        bfr[2] = (short)f2bf(w0.z); bfr[3] = (short)f2bf(w0.w);
        bfr[4] = (short)f2bf(w1.x); bfr[5] = (short)f2bf(w1.y);
        bfr[6] = (short)f2bf(w1.z); bfr[7] = (short)f2bf(w1.w);
#pragma unroll
        for (int mt = 0; mt < 8; ++mt) {
            short8 afr = *(const short8*)(abase + mt * 16 * FCIN + kk);
            acc[mt] = __builtin_amdgcn_mfma_f32_16x16x32_bf16(afr, bfr, acc[mt], 0, 0, 0);
        }
    }

    int j = n0 + lm;
#pragma unroll
    for (int mt = 0; mt < 8; ++mt) {
#pragma unroll
        for (int r = 0; r < 4; ++r) {
            int m = mt * 16 + kq * 4 + r;
            atomicAdd(&hidden[m * HID + j], acc[mt][r]);
        }
    }
}

// ---------------------------------------------------------------------------
// K4: FC2 + FC3 (fp32 VALU). d_out fp32: [0,8192)=out1, [8192,8448)=out.
// ---------------------------------------------------------------------------
__global__ __launch_bounds__(256) void fc2_kernel(
    const float* __restrict__ hidden,
    const float* __restrict__ W2, const float* __restrict__ b2,
    const float* __restrict__ W3, const float* __restrict__ b3,
    float* __restrict__ out)
{
    int tid = threadIdx.x;
    int c = tid & 63;
    int m = blockIdx.x * 4 + (tid >> 6);
    const float* hrow = hidden + m * HID;
    const float* wrow = W2 + c * HID;

    float acc = b2[c];
    for (int p = 0; p < HID; p += 4) {
        float4 wv = *(const float4*)(wrow + p);
        float4 hv = *(const float4*)(hrow + p);
        acc += hv.x * wv.x + hv.y * wv.y + hv.z * wv.z + hv.w * wv.w;
    }
    out[m * 64 + c] = acc;

    float t0 = acc * W3[c];
    float t1 = acc * W3[64 + c];
#pragma unroll
    for (int off = 32; off > 0; off >>= 1) {
        t0 += __shfl_down(t0, off, 64);
        t1 += __shfl_down(t1, off, 64);
    }
    if (c == 0) {
        float2 pk;
        pk.x = t0 + b3[0];
        pk.y = t1 + b3[1];
        *(float2*)(out + 8192 + m * 2) = pk;
    }
}

// ---------------------------------------------------------------------------
extern "C" void kernel_launch(void* const* d_in, const int* in_sizes, int n_in,
                              void* d_out, int out_size, void* d_ws, size_t ws_size,
                              hipStream_t stream) {
    const float* x  = (const float*)d_in[0];
    const float* Wq = (const float*)d_in[1];
    const float* bq = (const float*)d_in[2];
    const float* Wk = (const float*)d_in[3];
    const float* bk = (const float*)d_in[4];
    const float* Wv = (const float*)d_in[5];
    const float* bv = (const float*)d_in[6];
    const float* Wo = (const float*)d_in[7];
    const float* bo = (const float*)d_in[8];
    const float* W1 = (const float*)d_in[9];
    const float* b1 = (const float*)d_in[10];
    const float* W2 = (const float*)d_in[11];
    const float* b2 = (const float*)d_in[12];
    const float* W3 = (const float*)d_in[13];
    const float* b3 = (const float*)d_in[14];
    float* out = (float*)d_out;

    // ws layout (bytes), total 8,716,288:
    //   [0,         4,096,000)  avbf bf16 [64000][32]
    //   [4,096,000, 8,192,000)  flat bf16 [128][16000]
    //   [8,192,000, 8,716,288)  hidden fp32 [128][1024]
    u16*   avbf   = (u16*)d_ws;
    u16*   flat   = (u16*)((char*)d_ws + 4096000);
    float* hidden = (float*)((char*)d_ws + 8192000);

    attn_fused_mfma<<<dim3(1024), dim3(256), 0, stream>>>(
        x, Wq, bq, Wk, bk, Wv, bv, avbf);
    proj_mfma <<<dim3(1000), dim3(256), 0, stream>>>(avbf, Wo, bo, b1, flat, hidden);
    fc1_mfma  <<<dim3(400),  dim3(256), 0, stream>>>(flat, W1, hidden);
    fc2_kernel<<<dim3(32),   dim3(256), 0, stream>>>(hidden, W2, b2, W3, b3, out);
}

// Round 13
// 337.385 us; speedup vs baseline: 1.1622x; 1.1064x over previous
//
#include <hip/hip_runtime.h>

typedef unsigned short u16;
typedef __attribute__((ext_vector_type(8))) short short8;
typedef __attribute__((ext_vector_type(4))) float floatx4;

#define B_ 128
#define S_ 500
#define FCIN 16000
#define HID 1024
#define QSCL 0.72134752044448169f   // 0.5 * log2(e)

__device__ __forceinline__ float bf2f(u16 u) {
    union { unsigned u32; float f; } x;
    x.u32 = ((unsigned)u) << 16;
    return x.f;
}
__device__ __forceinline__ u16 f2bf(float f) {
    union { float f; unsigned u; } x;
    x.f = f;
    unsigned u = x.u;
    return (u16)((u + 0x7fff + ((u >> 16) & 1)) >> 16);
}

// ---------------------------------------------------------------------------
// K1: fused QKV + MFMA attention. Block = (b,h), 256 thr / 4 waves.
// v14: attn/proj/fc1 VERBATIM v11 (PASS, 373.3 us). Only fc2 changed.
//   Bisect conclusion from v12 (1e34) / v13 (NaN): the common new code was
//   inline-asm v_cvt_pk_bf16_f32 fed by float4 GLOBAL LOADS in proj/fc1
//   (attn's cvt_pk on VALU results passes; load-fed asm is blacklisted)
//   plus the fc2 rewrite. This round isolates fc2 (no asm, fully audited).
// ---------------------------------------------------------------------------
__global__ __launch_bounds__(256) void attn_fused_mfma(
    const float* __restrict__ x,
    const float* __restrict__ Wq, const float* __restrict__ bq,
    const float* __restrict__ Wk, const float* __restrict__ bk,
    const float* __restrict__ Wv, const float* __restrict__ bv,
    u16* __restrict__ avbf)
{
    __shared__ float sWb[12 * 32];   // rows 0-3 Wq, 4-7 Wk, 8-11 Wv (head h)
    __shared__ float sBb[12];
    __shared__ u16 sQ8[512 * 8];     // [q][qh0..3, ql0..3]
    __shared__ u16 sK8[512 * 8];     // [key][kh0..3, kl0..3]
    __shared__ u16 sVT[5 * 520];     // [vcol][key]; row 4 = ones (keys<500)

    int tid = threadIdx.x;
    int bh = blockIdx.x, b = bh >> 3, h = bh & 7;

    for (int i = tid; i < 384; i += 256) {
        int r = i >> 5, d = i & 31;
        const float* src = (r < 4) ? (Wq + (h * 4 + r) * 32)
                         : (r < 8) ? (Wk + (h * 4 + r - 4) * 32)
                                   : (Wv + (h * 4 + r - 8) * 32);
        sWb[r * 32 + d] = src[d];
    }
    if (tid < 12)
        sBb[tid] = (tid < 4) ? bq[h * 4 + tid]
                 : (tid < 8) ? bk[h * 4 + tid - 4] : bv[h * 4 + tid - 8];
    if (tid < 32) sVT[(tid >> 3) * 520 + 512 + (tid & 7)] = 0;
    for (int i = tid; i < 520; i += 256)             // ones row (denominator);
        sVT[4 * 520 + i] = (i < S_) ? (u16)0x3F80 : (u16)0;  // pad keys excluded
    __syncthreads();

    for (int s = tid; s < 512; s += 256) {
        bool valid = (s < S_);
        const float* xr = x + ((size_t)b * S_ + (valid ? s : 0)) * 32;
        float4 xv[8];
#pragma unroll
        for (int cc = 0; cc < 8; ++cc) xv[cc] = *(const float4*)(xr + cc * 4);
        short8 qv, kv;
#pragma unroll
        for (int r = 0; r < 12; ++r) {
            float acc = sBb[r];
            const float4* w4 = (const float4*)(sWb + r * 32);
#pragma unroll
            for (int cc = 0; cc < 8; ++cc) {
                float4 w = w4[cc];
                acc += xv[cc].x * w.x + xv[cc].y * w.y
                     + xv[cc].z * w.z + xv[cc].w * w.w;
            }
            if (!valid) acc = 0.f;
            if (r < 4) {
                float v = acc * QSCL;
                u16 hi = f2bf(v);
                qv[r]     = (short)hi;
                qv[4 + r] = (short)f2bf(v - bf2f(hi));
            } else if (r < 8) {
                int j = r - 4;
                u16 hi = f2bf(acc);
                kv[j]     = (short)hi;
                kv[4 + j] = (short)f2bf(acc - bf2f(hi));
            } else {
                sVT[(r - 8) * 520 + s] = f2bf(acc);
            }
        }
        *(short8*)(sQ8 + s * 8) = qv;    // one b128 store, conflict-free
        *(short8*)(sK8 + s * 8) = kv;
    }
    __syncthreads();

    int wid = tid >> 6, lane = tid & 63;
    int ln = lane & 15, kq = lane >> 4;
    const short8 z8 = {0, 0, 0, 0, 0, 0, 0, 0};
    floatx4 zero = {0.f, 0.f, 0.f, 0.f};

    for (int ii = 0; ii < 4; ++ii) {
        int qtA = wid + 8 * ii;                      // q-tiles [0,32), pairwise
        int qtB = qtA + 4;
        short8 qfA = z8, qfB = z8;
        if (kq == 0) {
            qfA = *(const short8*)(sQ8 + (qtA * 16 + ln) * 8);
            qfB = *(const short8*)(sQ8 + (qtB * 16 + ln) * 8);
        }
        // swapped halves: cross terms kh*ql + kl*qh via B-side swap
        short8 qfsA = __builtin_shufflevector(qfA, qfA, 4, 5, 6, 7, 0, 1, 2, 3);
        short8 qfsB = __builtin_shufflevector(qfB, qfB, 4, 5, 6, 7, 0, 1, 2, 3);

        floatx4 accA = zero, accB = zero;

        for (int c = 0; c < 16; ++c) {
            short8 ka = z8, kb = z8;
            if (kq == 0) {
                ka = *(const short8*)(sK8 + ((2 * c) * 16 + ln) * 8);
                kb = *(const short8*)(sK8 + ((2 * c + 1) * 16 + ln) * 8);
            }

            // two independent score chains sharing ka/kb
            floatx4 s1A = __builtin_amdgcn_mfma_f32_16x16x32_bf16(ka, qfA, zero, 0, 0, 0);
            s1A = __builtin_amdgcn_mfma_f32_16x16x32_bf16(ka, qfsA, s1A, 0, 0, 0);
            floatx4 s2A = __builtin_amdgcn_mfma_f32_16x16x32_bf16(kb, qfA, zero, 0, 0, 0);
            s2A = __builtin_amdgcn_mfma_f32_16x16x32_bf16(kb, qfsA, s2A, 0, 0, 0);
            floatx4 s1B = __builtin_amdgcn_mfma_f32_16x16x32_bf16(ka, qfB, zero, 0, 0, 0);
            s1B = __builtin_amdgcn_mfma_f32_16x16x32_bf16(ka, qfsB, s1B, 0, 0, 0);
            floatx4 s2B = __builtin_amdgcn_mfma_f32_16x16x32_bf16(kb, qfB, zero, 0, 0, 0);
            s2B = __builtin_amdgcn_mfma_f32_16x16x32_bf16(kb, qfsB, s2B, 0, 0, 0);

            // C layout: col=ln=q, row=kq*4+r = local key
            float eA10 = exp2f(s1A[0]), eA11 = exp2f(s1A[1]),
                  eA12 = exp2f(s1A[2]), eA13 = exp2f(s1A[3]);
            float eA20 = exp2f(s2A[0]), eA21 = exp2f(s2A[1]),
                  eA22 = exp2f(s2A[2]), eA23 = exp2f(s2A[3]);
            float eB10 = exp2f(s1B[0]), eB11 = exp2f(s1B[1]),
                  eB12 = exp2f(s1B[2]), eB13 = exp2f(s1B[3]);
            float eB20 = exp2f(s2B[0]), eB21 = exp2f(s2B[1]),
                  eB22 = exp2f(s2B[2]), eB23 = exp2f(s2B[3]);

            unsigned dA1a, dA1b, dA2a, dA2b, dB1a, dB1b, dB2a, dB2b;
            asm("v_cvt_pk_bf16_f32 %0, %1, %2" : "=v"(dA1a) : "v"(eA10), "v"(eA11));
            asm("v_cvt_pk_bf16_f32 %0, %1, %2" : "=v"(dA1b) : "v"(eA12), "v"(eA13));
            asm("v_cvt_pk_bf16_f32 %0, %1, %2" : "=v"(dA2a) : "v"(eA20), "v"(eA21));
            asm("v_cvt_pk_bf16_f32 %0, %1, %2" : "=v"(dA2b) : "v"(eA22), "v"(eA23));
            asm("v_cvt_pk_bf16_f32 %0, %1, %2" : "=v"(dB1a) : "v"(eB10), "v"(eB11));
            asm("v_cvt_pk_bf16_f32 %0, %1, %2" : "=v"(dB1b) : "v"(eB12), "v"(eB13));
            asm("v_cvt_pk_bf16_f32 %0, %1, %2" : "=v"(dB2a) : "v"(eB20), "v"(eB21));
            asm("v_cvt_pk_bf16_f32 %0, %1, %2" : "=v"(dB2b) : "v"(eB22), "v"(eB23));

            // redistribute so lane(ln,kq) holds P^T[k=kq*8..kq*8+7][q=ln]
            asm("v_permlane32_swap_b32 %0, %1" : "+v"(dA1a), "+v"(dA2a));
            asm("v_permlane32_swap_b32 %0, %1" : "+v"(dA1b), "+v"(dA2b));
            asm("v_permlane16_swap_b32 %0, %1" : "+v"(dA1a), "+v"(dA2a));
            asm("v_permlane16_swap_b32 %0, %1" : "+v"(dA1b), "+v"(dA2b));
            asm("v_permlane32_swap_b32 %0, %1" : "+v"(dB1a), "+v"(dB2a));
            asm("v_permlane32_swap_b32 %0, %1" : "+v"(dB1b), "+v"(dB2b));
            asm("v_permlane16_swap_b32 %0, %1" : "+v"(dB1a), "+v"(dB2a));
            asm("v_permlane16_swap_b32 %0, %1" : "+v"(dB1b), "+v"(dB2b));

            union { short8 s8; unsigned u[4]; } puA, puB;
            puA.u[0] = dA1a; puA.u[1] = dA1b; puA.u[2] = dA2a; puA.u[3] = dA2b;
            puB.u[0] = dB1a; puB.u[1] = dB1b; puB.u[2] = dB2a; puB.u[3] = dB2b;
            short8 pfA = puA.s8, pfB = puB.s8;

            // A rows 0-3 = V cols, row 4 = ones (0 for pad keys) ->
            // C row 4 accumulates the softmax denominator. vf shared A/B.
            short8 vf = z8;
            if (ln < 5)
                vf = *(const short8*)(sVT + ln * 520 + c * 32 + kq * 8);
            accA = __builtin_amdgcn_mfma_f32_16x16x32_bf16(vf, pfA, accA, 0, 0, 0);
            accB = __builtin_amdgcn_mfma_f32_16x16x32_bf16(vf, pfB, accB, 0, 0, 0);
        }

        // denominator = C row 4 col ln = lane (16+ln) acc[0]
        float rsA = __shfl(accA[0], ln + 16, 64);
        float rsB = __shfl(accB[0], ln + 16, 64);

        int qA = qtA * 16 + ln;
        if (kq == 0 && qA < S_) {                    // D rows 0-3 = vcols
            float inv = 1.0f / rsA;
            uint2 pk;
            pk.x = (unsigned)f2bf(accA[0] * inv) | ((unsigned)f2bf(accA[1] * inv) << 16);
            pk.y = (unsigned)f2bf(accA[2] * inv) | ((unsigned)f2bf(accA[3] * inv) << 16);
            *(uint2*)(avbf + ((size_t)(b * S_ + qA) * 32 + h * 4)) = pk;
        }
        int qB = qtB * 16 + ln;
        if (kq == 0 && qB < S_) {
            float inv = 1.0f / rsB;
            uint2 pk;
            pk.x = (unsigned)f2bf(accB[0] * inv) | ((unsigned)f2bf(accB[1] * inv) << 16);
            pk.y = (unsigned)f2bf(accB[2] * inv) | ((unsigned)f2bf(accB[3] * inv) << 16);
            *(uint2*)(avbf + ((size_t)(b * S_ + qB) * 32 + h * 4)) = pk;
        }
    }
}

// ---------------------------------------------------------------------------
// K2: output projection via MFMA: flat = av @ Wo^T + bo (bf16 out).
// Also inits hidden[m][j] = b1[j] for fc1's atomic accumulation.
// (v11 verbatim — manual f2bf; load-fed asm cvt_pk blacklisted.)
// ---------------------------------------------------------------------------
__global__ __launch_bounds__(256) void proj_mfma(
    const u16* __restrict__ avbf, const float* __restrict__ Wo,
    const float* __restrict__ bo, const float* __restrict__ b1,
    u16* __restrict__ flat, float* __restrict__ hidden)
{
    int tid = threadIdx.x;
    int gid = blockIdx.x * 256 + tid;
    if (gid < B_ * HID) hidden[gid] = b1[gid & (HID - 1)];

    int wid = tid >> 6, lane = tid & 63;
    int lm = lane & 15, kq = lane >> 4;
    int m0 = (blockIdx.x * 4 + wid) * 16;

    short8 af = *(const short8*)(avbf + (size_t)(m0 + lm) * 32 + kq * 8);
    floatx4 zero = {0.f, 0.f, 0.f, 0.f};
#pragma unroll
    for (int t2 = 0; t2 < 2; ++t2) {
        int d = t2 * 16 + lm;
        const float* wr = Wo + d * 32 + kq * 8;
        float4 w0 = *(const float4*)(wr);
        float4 w1 = *(const float4*)(wr + 4);
        short8 bf;
        bf[0] = (short)f2bf(w0.x); bf[1] = (short)f2bf(w0.y);
        bf[2] = (short)f2bf(w0.z); bf[3] = (short)f2bf(w0.w);
        bf[4] = (short)f2bf(w1.x); bf[5] = (short)f2bf(w1.y);
        bf[6] = (short)f2bf(w1.z); bf[7] = (short)f2bf(w1.w);
        floatx4 acc = __builtin_amdgcn_mfma_f32_16x16x32_bf16(af, bf, zero, 0, 0, 0);
        float bias = bo[d];
#pragma unroll
        for (int r = 0; r < 4; ++r) {
            int row = m0 + kq * 4 + r;
            flat[(size_t)row * 32 + d] = f2bf(acc[r] + bias);
        }
    }
}

// ---------------------------------------------------------------------------
// K3: FC1 via MFMA split-K (25 k-chunks x 16 n-groups = 400 blocks).
// (v11 verbatim — manual f2bf; load-fed asm cvt_pk blacklisted.)
// ---------------------------------------------------------------------------
__global__ __launch_bounds__(256) void fc1_mfma(
    const u16* __restrict__ flatbf, const float* __restrict__ W1,
    float* __restrict__ hidden)
{
    int tid = threadIdx.x;
    int wid = tid >> 6, lane = tid & 63;
    int lm = lane & 15, kq = lane >> 4;
    int ng = blockIdx.x & 15, kc = blockIdx.x >> 4;   // kc in [0,25)
    int n0 = ng * 64 + wid * 16;

    floatx4 acc[8];
#pragma unroll
    for (int mt = 0; mt < 8; ++mt) acc[mt] = (floatx4){0.f, 0.f, 0.f, 0.f};

    const float* wrow = W1 + (size_t)(n0 + lm) * FCIN;
    const u16*  abase = flatbf + lm * FCIN;

    for (int step = 0; step < 20; ++step) {
        int kk = kc * 640 + step * 32 + kq * 8;
        float4 w0 = *(const float4*)(wrow + kk);
        float4 w1 = *(const float4*)(wrow + kk + 4);
        short8 bfr;
        bfr[0] = (short)f2bf(w0.x); bfr[1] = (short)f2bf(w0.y);
        bfr[2] = (short)f2bf(w0.z); bfr[3] = (short)f2bf(w0.w);
        bfr[4] = (short)f2bf(w1.x); bfr[5] = (short)f2bf(w1.y);
        bfr[6] = (short)f2bf(w1.z); bfr[7] = (short)f2bf(w1.w);
#pragma unroll
        for (int mt = 0; mt < 8; ++mt) {
            short8 afr = *(const short8*)(abase + mt * 16 * FCIN + kk);
            acc[mt] = __builtin_amdgcn_mfma_f32_16x16x32_bf16(afr, bfr, acc[mt], 0, 0, 0);
        }
    }

    int j = n0 + lm;
#pragma unroll
    for (int mt = 0; mt < 8; ++mt) {
#pragma unroll
        for (int r = 0; r < 4; ++r) {
            int m = mt * 16 + kq * 4 + r;
            atomicAdd(&hidden[m * HID + j], acc[mt][r]);
        }
    }
}

// ---------------------------------------------------------------------------
// K4: FC2 + FC3 (fp32 VALU). d_out fp32: [0,8192)=out1, [8192,8448)=out.
// v14: 128 blocks (1 m-row each), 4 warps split HID 4-way + LDS reduce.
//   Old: 32 blocks = 8/256 CUs busy, 1024-elem serial dot per thread.
// ---------------------------------------------------------------------------
__global__ __launch_bounds__(256) void fc2_kernel(
    const float* __restrict__ hidden,
    const float* __restrict__ W2, const float* __restrict__ b2,
    const float* __restrict__ W3, const float* __restrict__ b3,
    float* __restrict__ out)
{
    __shared__ float red[4][64];
    int tid = threadIdx.x;
    int c = tid & 63;
    int w = tid >> 6;                    // HID quarter
    int m = blockIdx.x;                  // 128 blocks
    const float* hrow = hidden + m * HID + w * 256;
    const float* wrow = W2 + c * HID + w * 256;

    float acc = 0.f;
    for (int p = 0; p < 256; p += 4) {
        float4 wv = *(const float4*)(wrow + p);
        float4 hv = *(const float4*)(hrow + p);
        acc += hv.x * wv.x + hv.y * wv.y + hv.z * wv.z + hv.w * wv.w;
    }
    red[w][c] = acc;
    __syncthreads();
    if (w == 0) {
        float a = red[0][c] + red[1][c] + red[2][c] + red[3][c] + b2[c];
        out[m * 64 + c] = a;

        float t0 = a * W3[c];
        float t1 = a * W3[64 + c];
#pragma unroll
        for (int off = 32; off > 0; off >>= 1) {
            t0 += __shfl_down(t0, off, 64);
            t1 += __shfl_down(t1, off, 64);
        }
        if (c == 0) {
            float2 pk;
            pk.x = t0 + b3[0];
            pk.y = t1 + b3[1];
            *(float2*)(out + 8192 + m * 2) = pk;
        }
    }
}

// ---------------------------------------------------------------------------
extern "C" void kernel_launch(void* const* d_in, const int* in_sizes, int n_in,
                              void* d_out, int out_size, void* d_ws, size_t ws_size,
                              hipStream_t stream) {
    const float* x  = (const float*)d_in[0];
    const float* Wq = (const float*)d_in[1];
    const float* bq = (const float*)d_in[2];
    const float* Wk = (const float*)d_in[3];
    const float* bk = (const float*)d_in[4];
    const float* Wv = (const float*)d_in[5];
    const float* bv = (const float*)d_in[6];
    const float* Wo = (const float*)d_in[7];
    const float* bo = (const float*)d_in[8];
    const float* W1 = (const float*)d_in[9];
    const float* b1 = (const float*)d_in[10];
    const float* W2 = (const float*)d_in[11];
    const float* b2 = (const float*)d_in[12];
    const float* W3 = (const float*)d_in[13];
    const float* b3 = (const float*)d_in[14];
    float* out = (float*)d_out;

    // ws layout (bytes), total 8,716,288:
    //   [0,         4,096,000)  avbf bf16 [64000][32]
    //   [4,096,000, 8,192,000)  flat bf16 [128][16000]
    //   [8,192,000, 8,716,288)  hidden fp32 [128][1024]
    u16*   avbf   = (u16*)d_ws;
    u16*   flat   = (u16*)((char*)d_ws + 4096000);
    float* hidden = (float*)((char*)d_ws + 8192000);

    attn_fused_mfma<<<dim3(1024), dim3(256), 0, stream>>>(
        x, Wq, bq, Wk, bk, Wv, bv, avbf);
    proj_mfma <<<dim3(1000), dim3(256), 0, stream>>>(avbf, Wo, bo, b1, flat, hidden);
    fc1_mfma  <<<dim3(400),  dim3(256), 0, stream>>>(flat, W1, hidden);
    fc2_kernel<<<dim3(128),  dim3(256), 0, stream>>>(hidden, W2, b2, W3, b3, out);
}

// Round 14
// 320.808 us; speedup vs baseline: 1.2222x; 1.0517x over previous
//
#include <hip/hip_runtime.h>

typedef unsigned short u16;
typedef __attribute__((ext_vector_type(8))) short short8;
typedef __attribute__((ext_vector_type(4))) float floatx4;

#define B_ 128
#define S_ 500
#define FCIN 16000
#define HID 1024
#define QSCL 0.72134752044448169f   // 0.5 * log2(e)

__device__ __forceinline__ float bf2f(u16 u) {
    union { unsigned u32; float f; } x;
    x.u32 = ((unsigned)u) << 16;
    return x.f;
}
__device__ __forceinline__ u16 f2bf(float f) {
    union { float f; unsigned u; } x;
    x.f = f;
    unsigned u = x.u;
    return (u16)((u + 0x7fff + ((u >> 16) & 1)) >> 16);
}

// ---------------------------------------------------------------------------
// K1: fused QKV + MFMA attention. Block = (b,h), 256 thr / 4 waves.
// v15 = v14 with 4-way q-tile interleave using NAMED VARIABLES only.
//   v11's 2-way named-var interleave: PASS, 210->161 us. v12's 4-way used
//   short8 qf[4] arrays (rule #20: runtime-indexable ext_vector arrays ->
//   scratch; scratch + tied-"+v" asm = garbage) and failed 1e34. This is
//   the same chain body cloned 4x with suffixes A/B/C/D — zero arrays,
//   zero new asm patterns. ka/kb/vf LDS loads amortized over 4 chains.
//   Blacklisted this session: waves_per_eu bounds (RF-split spill),
//   load-fed asm cvt_pk (v12/v13 NaN), ext_vector arrays in asm regions.
// ---------------------------------------------------------------------------
__global__ __launch_bounds__(256) void attn_fused_mfma(
    const float* __restrict__ x,
    const float* __restrict__ Wq, const float* __restrict__ bq,
    const float* __restrict__ Wk, const float* __restrict__ bk,
    const float* __restrict__ Wv, const float* __restrict__ bv,
    u16* __restrict__ avbf)
{
    __shared__ float sWb[12 * 32];   // rows 0-3 Wq, 4-7 Wk, 8-11 Wv (head h)
    __shared__ float sBb[12];
    __shared__ u16 sQ8[512 * 8];     // [q][qh0..3, ql0..3]
    __shared__ u16 sK8[512 * 8];     // [key][kh0..3, kl0..3]
    __shared__ u16 sVT[5 * 520];     // [vcol][key]; row 4 = ones (keys<500)

    int tid = threadIdx.x;
    int bh = blockIdx.x, b = bh >> 3, h = bh & 7;

    for (int i = tid; i < 384; i += 256) {
        int r = i >> 5, d = i & 31;
        const float* src = (r < 4) ? (Wq + (h * 4 + r) * 32)
                         : (r < 8) ? (Wk + (h * 4 + r - 4) * 32)
                                   : (Wv + (h * 4 + r - 8) * 32);
        sWb[r * 32 + d] = src[d];
    }
    if (tid < 12)
        sBb[tid] = (tid < 4) ? bq[h * 4 + tid]
                 : (tid < 8) ? bk[h * 4 + tid - 4] : bv[h * 4 + tid - 8];
    if (tid < 32) sVT[(tid >> 3) * 520 + 512 + (tid & 7)] = 0;
    for (int i = tid; i < 520; i += 256)             // ones row (denominator);
        sVT[4 * 520 + i] = (i < S_) ? (u16)0x3F80 : (u16)0;  // pad keys excluded
    __syncthreads();

    for (int s = tid; s < 512; s += 256) {
        bool valid = (s < S_);
        const float* xr = x + ((size_t)b * S_ + (valid ? s : 0)) * 32;
        float4 xv[8];
#pragma unroll
        for (int cc = 0; cc < 8; ++cc) xv[cc] = *(const float4*)(xr + cc * 4);
        short8 qv, kv;
#pragma unroll
        for (int r = 0; r < 12; ++r) {
            float acc = sBb[r];
            const float4* w4 = (const float4*)(sWb + r * 32);
#pragma unroll
            for (int cc = 0; cc < 8; ++cc) {
                float4 w = w4[cc];
                acc += xv[cc].x * w.x + xv[cc].y * w.y
                     + xv[cc].z * w.z + xv[cc].w * w.w;
            }
            if (!valid) acc = 0.f;
            if (r < 4) {
                float v = acc * QSCL;
                u16 hi = f2bf(v);
                qv[r]     = (short)hi;
                qv[4 + r] = (short)f2bf(v - bf2f(hi));
            } else if (r < 8) {
                int j = r - 4;
                u16 hi = f2bf(acc);
                kv[j]     = (short)hi;
                kv[4 + j] = (short)f2bf(acc - bf2f(hi));
            } else {
                sVT[(r - 8) * 520 + s] = f2bf(acc);
            }
        }
        *(short8*)(sQ8 + s * 8) = qv;    // one b128 store, conflict-free
        *(short8*)(sK8 + s * 8) = kv;
    }
    __syncthreads();

    int wid = tid >> 6, lane = tid & 63;
    int ln = lane & 15, kq = lane >> 4;
    const short8 z8 = {0, 0, 0, 0, 0, 0, 0, 0};
    floatx4 zero = {0.f, 0.f, 0.f, 0.f};

    for (int ii = 0; ii < 2; ++ii) {
        int qtA = wid + 16 * ii;                     // tiles wid + 16*ii + {0,4,8,12}
        int qtB = qtA + 4;
        int qtC = qtA + 8;
        int qtD = qtA + 12;
        short8 qfA = z8, qfB = z8, qfC = z8, qfD = z8;
        if (kq == 0) {
            qfA = *(const short8*)(sQ8 + (qtA * 16 + ln) * 8);
            qfB = *(const short8*)(sQ8 + (qtB * 16 + ln) * 8);
            qfC = *(const short8*)(sQ8 + (qtC * 16 + ln) * 8);
            qfD = *(const short8*)(sQ8 + (qtD * 16 + ln) * 8);
        }
        // swapped halves: cross terms kh*ql + kl*qh via B-side swap
        short8 qfsA = __builtin_shufflevector(qfA, qfA, 4, 5, 6, 7, 0, 1, 2, 3);
        short8 qfsB = __builtin_shufflevector(qfB, qfB, 4, 5, 6, 7, 0, 1, 2, 3);
        short8 qfsC = __builtin_shufflevector(qfC, qfC, 4, 5, 6, 7, 0, 1, 2, 3);
        short8 qfsD = __builtin_shufflevector(qfD, qfD, 4, 5, 6, 7, 0, 1, 2, 3);

        floatx4 accA = zero, accB = zero, accC = zero, accD = zero;

        for (int c = 0; c < 16; ++c) {
            short8 ka = z8, kb = z8;
            if (kq == 0) {
                ka = *(const short8*)(sK8 + ((2 * c) * 16 + ln) * 8);
                kb = *(const short8*)(sK8 + ((2 * c + 1) * 16 + ln) * 8);
            }
            short8 vf = z8;                  // shared by all 4 chains
            if (ln < 5)
                vf = *(const short8*)(sVT + ln * 520 + c * 32 + kq * 8);

            // ---- chain A ----
            floatx4 s1A = __builtin_amdgcn_mfma_f32_16x16x32_bf16(ka, qfA, zero, 0, 0, 0);
            s1A = __builtin_amdgcn_mfma_f32_16x16x32_bf16(ka, qfsA, s1A, 0, 0, 0);
            floatx4 s2A = __builtin_amdgcn_mfma_f32_16x16x32_bf16(kb, qfA, zero, 0, 0, 0);
            s2A = __builtin_amdgcn_mfma_f32_16x16x32_bf16(kb, qfsA, s2A, 0, 0, 0);
            float eA10 = exp2f(s1A[0]), eA11 = exp2f(s1A[1]),
                  eA12 = exp2f(s1A[2]), eA13 = exp2f(s1A[3]);
            float eA20 = exp2f(s2A[0]), eA21 = exp2f(s2A[1]),
                  eA22 = exp2f(s2A[2]), eA23 = exp2f(s2A[3]);
            unsigned dA1a, dA1b, dA2a, dA2b;
            asm("v_cvt_pk_bf16_f32 %0, %1, %2" : "=v"(dA1a) : "v"(eA10), "v"(eA11));
            asm("v_cvt_pk_bf16_f32 %0, %1, %2" : "=v"(dA1b) : "v"(eA12), "v"(eA13));
            asm("v_cvt_pk_bf16_f32 %0, %1, %2" : "=v"(dA2a) : "v"(eA20), "v"(eA21));
            asm("v_cvt_pk_bf16_f32 %0, %1, %2" : "=v"(dA2b) : "v"(eA22), "v"(eA23));
            asm("v_permlane32_swap_b32 %0, %1" : "+v"(dA1a), "+v"(dA2a));
            asm("v_permlane32_swap_b32 %0, %1" : "+v"(dA1b), "+v"(dA2b));
            asm("v_permlane16_swap_b32 %0, %1" : "+v"(dA1a), "+v"(dA2a));
            asm("v_permlane16_swap_b32 %0, %1" : "+v"(dA1b), "+v"(dA2b));
            union { short8 s8; unsigned u[4]; } puA;
            puA.u[0] = dA1a; puA.u[1] = dA1b; puA.u[2] = dA2a; puA.u[3] = dA2b;
            accA = __builtin_amdgcn_mfma_f32_16x16x32_bf16(vf, puA.s8, accA, 0, 0, 0);

            // ---- chain B ----
            floatx4 s1B = __builtin_amdgcn_mfma_f32_16x16x32_bf16(ka, qfB, zero, 0, 0, 0);
            s1B = __builtin_amdgcn_mfma_f32_16x16x32_bf16(ka, qfsB, s1B, 0, 0, 0);
            floatx4 s2B = __builtin_amdgcn_mfma_f32_16x16x32_bf16(kb, qfB, zero, 0, 0, 0);
            s2B = __builtin_amdgcn_mfma_f32_16x16x32_bf16(kb, qfsB, s2B, 0, 0, 0);
            float eB10 = exp2f(s1B[0]), eB11 = exp2f(s1B[1]),
                  eB12 = exp2f(s1B[2]), eB13 = exp2f(s1B[3]);
            float eB20 = exp2f(s2B[0]), eB21 = exp2f(s2B[1]),
                  eB22 = exp2f(s2B[2]), eB23 = exp2f(s2B[3]);
            unsigned dB1a, dB1b, dB2a, dB2b;
            asm("v_cvt_pk_bf16_f32 %0, %1, %2" : "=v"(dB1a) : "v"(eB10), "v"(eB11));
            asm("v_cvt_pk_bf16_f32 %0, %1, %2" : "=v"(dB1b) : "v"(eB12), "v"(eB13));
            asm("v_cvt_pk_bf16_f32 %0, %1, %2" : "=v"(dB2a) : "v"(eB20), "v"(eB21));
            asm("v_cvt_pk_bf16_f32 %0, %1, %2" : "=v"(dB2b) : "v"(eB22), "v"(eB23));
            asm("v_permlane32_swap_b32 %0, %1" : "+v"(dB1a), "+v"(dB2a));
            asm("v_permlane32_swap_b32 %0, %1" : "+v"(dB1b), "+v"(dB2b));
            asm("v_permlane16_swap_b32 %0, %1" : "+v"(dB1a), "+v"(dB2a));
            asm("v_permlane16_swap_b32 %0, %1" : "+v"(dB1b), "+v"(dB2b));
            union { short8 s8; unsigned u[4]; } puB;
            puB.u[0] = dB1a; puB.u[1] = dB1b; puB.u[2] = dB2a; puB.u[3] = dB2b;
            accB = __builtin_amdgcn_mfma_f32_16x16x32_bf16(vf, puB.s8, accB, 0, 0, 0);

            // ---- chain C ----
            floatx4 s1C = __builtin_amdgcn_mfma_f32_16x16x32_bf16(ka, qfC, zero, 0, 0, 0);
            s1C = __builtin_amdgcn_mfma_f32_16x16x32_bf16(ka, qfsC, s1C, 0, 0, 0);
            floatx4 s2C = __builtin_amdgcn_mfma_f32_16x16x32_bf16(kb, qfC, zero, 0, 0, 0);
            s2C = __builtin_amdgcn_mfma_f32_16x16x32_bf16(kb, qfsC, s2C, 0, 0, 0);
            float eC10 = exp2f(s1C[0]), eC11 = exp2f(s1C[1]),
                  eC12 = exp2f(s1C[2]), eC13 = exp2f(s1C[3]);
            float eC20 = exp2f(s2C[0]), eC21 = exp2f(s2C[1]),
                  eC22 = exp2f(s2C[2]), eC23 = exp2f(s2C[3]);
            unsigned dC1a, dC1b, dC2a, dC2b;
            asm("v_cvt_pk_bf16_f32 %0, %1, %2" : "=v"(dC1a) : "v"(eC10), "v"(eC11));
            asm("v_cvt_pk_bf16_f32 %0, %1, %2" : "=v"(dC1b) : "v"(eC12), "v"(eC13));
            asm("v_cvt_pk_bf16_f32 %0, %1, %2" : "=v"(dC2a) : "v"(eC20), "v"(eC21));
            asm("v_cvt_pk_bf16_f32 %0, %1, %2" : "=v"(dC2b) : "v"(eC22), "v"(eC23));
            asm("v_permlane32_swap_b32 %0, %1" : "+v"(dC1a), "+v"(dC2a));
            asm("v_permlane32_swap_b32 %0, %1" : "+v"(dC1b), "+v"(dC2b));
            asm("v_permlane16_swap_b32 %0, %1" : "+v"(dC1a), "+v"(dC2a));
            asm("v_permlane16_swap_b32 %0, %1" : "+v"(dC1b), "+v"(dC2b));
            union { short8 s8; unsigned u[4]; } puC;
            puC.u[0] = dC1a; puC.u[1] = dC1b; puC.u[2] = dC2a; puC.u[3] = dC2b;
            accC = __builtin_amdgcn_mfma_f32_16x16x32_bf16(vf, puC.s8, accC, 0, 0, 0);

            // ---- chain D ----
            floatx4 s1D = __builtin_amdgcn_mfma_f32_16x16x32_bf16(ka, qfD, zero, 0, 0, 0);
            s1D = __builtin_amdgcn_mfma_f32_16x16x32_bf16(ka, qfsD, s1D, 0, 0, 0);
            floatx4 s2D = __builtin_amdgcn_mfma_f32_16x16x32_bf16(kb, qfD, zero, 0, 0, 0);
            s2D = __builtin_amdgcn_mfma_f32_16x16x32_bf16(kb, qfsD, s2D, 0, 0, 0);
            float eD10 = exp2f(s1D[0]), eD11 = exp2f(s1D[1]),
                  eD12 = exp2f(s1D[2]), eD13 = exp2f(s1D[3]);
            float eD20 = exp2f(s2D[0]), eD21 = exp2f(s2D[1]),
                  eD22 = exp2f(s2D[2]), eD23 = exp2f(s2D[3]);
            unsigned dD1a, dD1b, dD2a, dD2b;
            asm("v_cvt_pk_bf16_f32 %0, %1, %2" : "=v"(dD1a) : "v"(eD10), "v"(eD11));
            asm("v_cvt_pk_bf16_f32 %0, %1, %2" : "=v"(dD1b) : "v"(eD12), "v"(eD13));
            asm("v_cvt_pk_bf16_f32 %0, %1, %2" : "=v"(dD2a) : "v"(eD20), "v"(eD21));
            asm("v_cvt_pk_bf16_f32 %0, %1, %2" : "=v"(dD2b) : "v"(eD22), "v"(eD23));
            asm("v_permlane32_swap_b32 %0, %1" : "+v"(dD1a), "+v"(dD2a));
            asm("v_permlane32_swap_b32 %0, %1" : "+v"(dD1b), "+v"(dD2b));
            asm("v_permlane16_swap_b32 %0, %1" : "+v"(dD1a), "+v"(dD2a));
            asm("v_permlane16_swap_b32 %0, %1" : "+v"(dD1b), "+v"(dD2b));
            union { short8 s8; unsigned u[4]; } puD;
            puD.u[0] = dD1a; puD.u[1] = dD1b; puD.u[2] = dD2a; puD.u[3] = dD2b;
            accD = __builtin_amdgcn_mfma_f32_16x16x32_bf16(vf, puD.s8, accD, 0, 0, 0);
        }

        // denominator = C row 4 col ln = lane (16+ln) acc[0]
        float rsA = __shfl(accA[0], ln + 16, 64);
        float rsB = __shfl(accB[0], ln + 16, 64);
        float rsC = __shfl(accC[0], ln + 16, 64);
        float rsD = __shfl(accD[0], ln + 16, 64);

        int qA = qtA * 16 + ln;
        if (kq == 0 && qA < S_) {                    // D rows 0-3 = vcols
            float inv = 1.0f / rsA;
            uint2 pk;
            pk.x = (unsigned)f2bf(accA[0] * inv) | ((unsigned)f2bf(accA[1] * inv) << 16);
            pk.y = (unsigned)f2bf(accA[2] * inv) | ((unsigned)f2bf(accA[3] * inv) << 16);
            *(uint2*)(avbf + ((size_t)(b * S_ + qA) * 32 + h * 4)) = pk;
        }
        int qB = qtB * 16 + ln;
        if (kq == 0 && qB < S_) {
            float inv = 1.0f / rsB;
            uint2 pk;
            pk.x = (unsigned)f2bf(accB[0] * inv) | ((unsigned)f2bf(accB[1] * inv) << 16);
            pk.y = (unsigned)f2bf(accB[2] * inv) | ((unsigned)f2bf(accB[3] * inv) << 16);
            *(uint2*)(avbf + ((size_t)(b * S_ + qB) * 32 + h * 4)) = pk;
        }
        int qC = qtC * 16 + ln;
        if (kq == 0 && qC < S_) {
            float inv = 1.0f / rsC;
            uint2 pk;
            pk.x = (unsigned)f2bf(accC[0] * inv) | ((unsigned)f2bf(accC[1] * inv) << 16);
            pk.y = (unsigned)f2bf(accC[2] * inv) | ((unsigned)f2bf(accC[3] * inv) << 16);
            *(uint2*)(avbf + ((size_t)(b * S_ + qC) * 32 + h * 4)) = pk;
        }
        int qD = qtD * 16 + ln;
        if (kq == 0 && qD < S_) {
            float inv = 1.0f / rsD;
            uint2 pk;
            pk.x = (unsigned)f2bf(accD[0] * inv) | ((unsigned)f2bf(accD[1] * inv) << 16);
            pk.y = (unsigned)f2bf(accD[2] * inv) | ((unsigned)f2bf(accD[3] * inv) << 16);
            *(uint2*)(avbf + ((size_t)(b * S_ + qD) * 32 + h * 4)) = pk;
        }
    }
}

// ---------------------------------------------------------------------------
// K2: output projection via MFMA: flat = av @ Wo^T + bo (bf16 out).
// Also inits hidden[m][j] = b1[j] for fc1's atomic accumulation.
// (v11 verbatim — manual f2bf; load-fed asm cvt_pk blacklisted.)
// ---------------------------------------------------------------------------
__global__ __launch_bounds__(256) void proj_mfma(
    const u16* __restrict__ avbf, const float* __restrict__ Wo,
    const float* __restrict__ bo, const float* __restrict__ b1,
    u16* __restrict__ flat, float* __restrict__ hidden)
{
    int tid = threadIdx.x;
    int gid = blockIdx.x * 256 + tid;
    if (gid < B_ * HID) hidden[gid] = b1[gid & (HID - 1)];

    int wid = tid >> 6, lane = tid & 63;
    int lm = lane & 15, kq = lane >> 4;
    int m0 = (blockIdx.x * 4 + wid) * 16;

    short8 af = *(const short8*)(avbf + (size_t)(m0 + lm) * 32 + kq * 8);
    floatx4 zero = {0.f, 0.f, 0.f, 0.f};
#pragma unroll
    for (int t2 = 0; t2 < 2; ++t2) {
        int d = t2 * 16 + lm;
        const float* wr = Wo + d * 32 + kq * 8;
        float4 w0 = *(const float4*)(wr);
        float4 w1 = *(const float4*)(wr + 4);
        short8 bf;
        bf[0] = (short)f2bf(w0.x); bf[1] = (short)f2bf(w0.y);
        bf[2] = (short)f2bf(w0.z); bf[3] = (short)f2bf(w0.w);
        bf[4] = (short)f2bf(w1.x); bf[5] = (short)f2bf(w1.y);
        bf[6] = (short)f2bf(w1.z); bf[7] = (short)f2bf(w1.w);
        floatx4 acc = __builtin_amdgcn_mfma_f32_16x16x32_bf16(af, bf, zero, 0, 0, 0);
        float bias = bo[d];
#pragma unroll
        for (int r = 0; r < 4; ++r) {
            int row = m0 + kq * 4 + r;
            flat[(size_t)row * 32 + d] = f2bf(acc[r] + bias);
        }
    }
}

// ---------------------------------------------------------------------------
// K3: FC1 via MFMA split-K (25 k-chunks x 16 n-groups = 400 blocks).
// (v11 verbatim — manual f2bf; load-fed asm cvt_pk blacklisted.)
// ---------------------------------------------------------------------------
__global__ __launch_bounds__(256) void fc1_mfma(
    const u16* __restrict__ flatbf, const float* __restrict__ W1,
    float* __restrict__ hidden)
{
    int tid = threadIdx.x;
    int wid = tid >> 6, lane = tid & 63;
    int lm = lane & 15, kq = lane >> 4;
    int ng = blockIdx.x & 15, kc = blockIdx.x >> 4;   // kc in [0,25)
    int n0 = ng * 64 + wid * 16;

    floatx4 acc[8];
#pragma unroll
    for (int mt = 0; mt < 8; ++mt) acc[mt] = (floatx4){0.f, 0.f, 0.f, 0.f};

    const float* wrow = W1 + (size_t)(n0 + lm) * FCIN;
    const u16*  abase = flatbf + lm * FCIN;

    for (int step = 0; step < 20; ++step) {
        int kk = kc * 640 + step * 32 + kq * 8;
        float4 w0 = *(const float4*)(wrow + kk);
        float4 w1 = *(const float4*)(wrow + kk + 4);
        short8 bfr;
        bfr[0] = (short)f2bf(w0.x); bfr[1] = (short)f2bf(w0.y);
        bfr[2] = (short)f2bf(w0.z); bfr[3] = (short)f2bf(w0.w);
        bfr[4] = (short)f2bf(w1.x); bfr[5] = (short)f2bf(w1.y);
        bfr[6] = (short)f2bf(w1.z); bfr[7] = (short)f2bf(w1.w);
#pragma unroll
        for (int mt = 0; mt < 8; ++mt) {
            short8 afr = *(const short8*)(abase + mt * 16 * FCIN + kk);
            acc[mt] = __builtin_amdgcn_mfma_f32_16x16x32_bf16(afr, bfr, acc[mt], 0, 0, 0);
        }
    }

    int j = n0 + lm;
#pragma unroll
    for (int mt = 0; mt < 8; ++mt) {
#pragma unroll
        for (int r = 0; r < 4; ++r) {
            int m = mt * 16 + kq * 4 + r;
            atomicAdd(&hidden[m * HID + j], acc[mt][r]);
        }
    }
}

// ---------------------------------------------------------------------------
// K4: FC2 + FC3 (fp32 VALU). d_out fp32: [0,8192)=out1, [8192,8448)=out.
// v14: 128 blocks (1 m-row each), 4 warps split HID 4-way + LDS reduce.
// ---------------------------------------------------------------------------
__global__ __launch_bounds__(256) void fc2_kernel(
    const float* __restrict__ hidden,
    const float* __restrict__ W2, const float* __restrict__ b2,
    const float* __restrict__ W3, const float* __restrict__ b3,
    float* __restrict__ out)
{
    __shared__ float red[4][64];
    int tid = threadIdx.x;
    int c = tid & 63;
    int w = tid >> 6;                    // HID quarter
    int m = blockIdx.x;                  // 128 blocks
    const float* hrow = hidden + m * HID + w * 256;
    const float* wrow = W2 + c * HID + w * 256;

    float acc = 0.f;
    for (int p = 0; p < 256; p += 4) {
        float4 wv = *(const float4*)(wrow + p);
        float4 hv = *(const float4*)(hrow + p);
        acc += hv.x * wv.x + hv.y * wv.y + hv.z * wv.z + hv.w * wv.w;
    }
    red[w][c] = acc;
    __syncthreads();
    if (w == 0) {
        float a = red[0][c] + red[1][c] + red[2][c] + red[3][c] + b2[c];
        out[m * 64 + c] = a;

        float t0 = a * W3[c];
        float t1 = a * W3[64 + c];
#pragma unroll
        for (int off = 32; off > 0; off >>= 1) {
            t0 += __shfl_down(t0, off, 64);
            t1 += __shfl_down(t1, off, 64);
        }
        if (c == 0) {
            float2 pk;
            pk.x = t0 + b3[0];
            pk.y = t1 + b3[1];
            *(float2*)(out + 8192 + m * 2) = pk;
        }
    }
}

// ---------------------------------------------------------------------------
extern "C" void kernel_launch(void* const* d_in, const int* in_sizes, int n_in,
                              void* d_out, int out_size, void* d_ws, size_t ws_size,
                              hipStream_t stream) {
    const float* x  = (const float*)d_in[0];
    const float* Wq = (const float*)d_in[1];
    const float* bq = (const float*)d_in[2];
    const float* Wk = (const float*)d_in[3];
    const float* bk = (const float*)d_in[4];
    const float* Wv = (const float*)d_in[5];
    const float* bv = (const float*)d_in[6];
    const float* Wo = (const float*)d_in[7];
    const float* bo = (const float*)d_in[8];
    const float* W1 = (const float*)d_in[9];
    const float* b1 = (const float*)d_in[10];
    const float* W2 = (const float*)d_in[11];
    const float* b2 = (const float*)d_in[12];
    const float* W3 = (const float*)d_in[13];
    const float* b3 = (const float*)d_in[14];
    float* out = (float*)d_out;

    // ws layout (bytes), total 8,716,288:
    //   [0,         4,096,000)  avbf bf16 [64000][32]
    //   [4,096,000, 8,192,000)  flat bf16 [128][16000]
    //   [8,192,000, 8,716,288)  hidden fp32 [128][1024]
    u16*   avbf   = (u16*)d_ws;
    u16*   flat   = (u16*)((char*)d_ws + 4096000);
    float* hidden = (float*)((char*)d_ws + 8192000);

    attn_fused_mfma<<<dim3(1024), dim3(256), 0, stream>>>(
        x, Wq, bq, Wk, bk, Wv, bv, avbf);
    proj_mfma <<<dim3(1000), dim3(256), 0, stream>>>(avbf, Wo, bo, b1, flat, hidden);
    fc1_mfma  <<<dim3(400),  dim3(256), 0, stream>>>(flat, W1, hidden);
    fc2_kernel<<<dim3(128),  dim3(256), 0, stream>>>(hidden, W2, b2, W3, b3, out);
}